// Round 1
// baseline (718.312 us; speedup 1.0000x reference)
//
#include <hip/hip_runtime.h>
#include <stdint.h>

#define T_ 2048
#define V_ 32000
#define D_ 1024
#define E_ 16
#define CAP_ 256
#define DFF_ 2048

typedef unsigned short u16;
typedef unsigned int u32;
typedef __bf16 bf16x8 __attribute__((ext_vector_type(8)));
typedef float f32x4 __attribute__((ext_vector_type(4)));

__device__ __forceinline__ u16 f2bf(float f){
  u32 u = __float_as_uint(f);
  u32 r = u + 0x7FFFu + ((u >> 16) & 1u);
  return (u16)(r >> 16);
}
__device__ __forceinline__ float bf2f(u16 s){ return __uint_as_float(((u32)s) << 16); }

__device__ __forceinline__ void gl_lds16(const void* g, void* l){
  __builtin_amdgcn_global_load_lds((const __attribute__((address_space(1))) void*)g,
                                   (__attribute__((address_space(3))) void*)l, 16, 0, 0);
}
__device__ __forceinline__ f32x4 mfma16(bf16x8 a, bf16x8 b, f32x4 c){
  return __builtin_amdgcn_mfma_f32_16x16x32_bf16(a, b, c, 0, 0, 0);
}
__device__ __forceinline__ float gelu_tanh(float x){
  float u = 0.7978845608028654f * (x + 0.044715f * x * x * x);
  return 0.5f * x * (1.0f + tanhf(u));
}

// ---------------- embedding lookup: h[t,:] = embed_W[ids[t],:] ----------------
__global__ __launch_bounds__(256) void k_embed(const int* __restrict__ ids,
    const float* __restrict__ W, float* __restrict__ h){
  int t = blockIdx.x;
  int d = threadIdx.x * 4;
  *(float4*)(h + (size_t)t*D_ + d) = *(const float4*)(W + (size_t)ids[t]*D_ + d);
}

// ---------------- embed_W fp32 -> bf16 (for final GEMM B) ----------------
__global__ __launch_bounds__(256) void k_cvtw(const float* __restrict__ W, u16* __restrict__ Wb){
  size_t i = ((size_t)blockIdx.x*256 + threadIdx.x)*8;
  float4 a = *(const float4*)(W + i);
  float4 b = *(const float4*)(W + i + 4);
  union { u16 s[8]; uint4 v; } p;
  p.s[0]=f2bf(a.x); p.s[1]=f2bf(a.y); p.s[2]=f2bf(a.z); p.s[3]=f2bf(a.w);
  p.s[4]=f2bf(b.x); p.s[5]=f2bf(b.y); p.s[6]=f2bf(b.z); p.s[7]=f2bf(b.w);
  *(uint4*)(Wb + i) = p.v;
}

// ---------------- router: logits, softmax top-2, mask ----------------
__global__ __launch_bounds__(256) void k_router(const float* __restrict__ h,
    const float* __restrict__ Wr, float* __restrict__ logits,
    unsigned char* __restrict__ mask, int* __restrict__ top2, float* __restrict__ p2){
  int w = threadIdx.x >> 6, l = threadIdx.x & 63;
  int t = blockIdx.x*4 + w;
  float acc[E_];
  #pragma unroll
  for (int e=0;e<E_;++e) acc[e]=0.f;
  const float* hrow = h + (size_t)t*D_;
  #pragma unroll
  for (int i=0;i<16;++i){
    int d = l + i*64;
    float hv = hrow[d];
    const float4* wr = (const float4*)(Wr + d*E_);
    float4 w0=wr[0], w1=wr[1], w2=wr[2], w3=wr[3];
    acc[0]+=hv*w0.x; acc[1]+=hv*w0.y; acc[2]+=hv*w0.z; acc[3]+=hv*w0.w;
    acc[4]+=hv*w1.x; acc[5]+=hv*w1.y; acc[6]+=hv*w1.z; acc[7]+=hv*w1.w;
    acc[8]+=hv*w2.x; acc[9]+=hv*w2.y; acc[10]+=hv*w2.z; acc[11]+=hv*w2.w;
    acc[12]+=hv*w3.x; acc[13]+=hv*w3.y; acc[14]+=hv*w3.z; acc[15]+=hv*w3.w;
  }
  #pragma unroll
  for (int off=32; off; off>>=1){
    #pragma unroll
    for (int e=0;e<E_;++e) acc[e] += __shfl_xor(acc[e], off, 64);
  }
  float mx = acc[0];
  #pragma unroll
  for (int e=1;e<E_;++e) mx = fmaxf(mx, acc[e]);
  float p[E_], s = 0.f;
  #pragma unroll
  for (int e=0;e<E_;++e){ p[e] = expf(acc[e]-mx); s += p[e]; }
  int i1 = 0; float v1 = acc[0];
  #pragma unroll
  for (int e=1;e<E_;++e) if (acc[e] > v1){ v1 = acc[e]; i1 = e; }
  int i2 = (i1==0)?1:0; float v2 = acc[i2];
  #pragma unroll
  for (int e=0;e<E_;++e) if (e!=i1 && e!=i2 && acc[e] > v2){ v2 = acc[e]; i2 = e; }
  if (l < E_){
    logits[t*E_+l] = acc[l];
    mask[t*E_+l] = (l==i1 || l==i2) ? 1 : 0;
  }
  if (l == 0){
    float inv = 1.f/s;
    top2[t*2] = i1; top2[t*2+1] = i2;
    p2[t*2] = p[i1]*inv; p2[t*2+1] = p[i2]*inv;
  }
}

__global__ __launch_bounds__(256) void k_init_etok(int* __restrict__ etok){
  etok[blockIdx.x*256 + threadIdx.x] = -1;
}

// ---------------- capacity selection: rank among masked tokens of my expert ----------------
__global__ __launch_bounds__(256) void k_capacity(const float* __restrict__ logits,
    const unsigned char* __restrict__ mask, const int* __restrict__ top2,
    int* __restrict__ kept, int* __restrict__ etok){
  int w = threadIdx.x >> 6, l = threadIdx.x & 63;
  int wid = blockIdx.x*4 + w;           // 0..4095
  int t = wid >> 1, k = wid & 1;
  int e = top2[t*2+k];
  float my = logits[t*E_+e];
  int cnt = 0;
  for (int t2 = l; t2 < T_; t2 += 64){
    if (mask[t2*E_+e]){
      float lg = logits[t2*E_+e];
      if (lg > my || (lg == my && t2 < t)) cnt++;
    }
  }
  #pragma unroll
  for (int off=32; off; off>>=1) cnt += __shfl_xor(cnt, off, 64);
  if (l == 0){
    if (cnt < CAP_){ kept[t*2+k] = cnt; etok[e*CAP_+cnt] = t; }
    else kept[t*2+k] = -1;
  }
}

// ---------------- gather tokens into expert buffers, split hi/lo bf16 ----------------
__global__ __launch_bounds__(256) void k_gather(const float* __restrict__ h,
    const int* __restrict__ etok, u16* __restrict__ xhi, u16* __restrict__ xlo){
  int rc = blockIdx.x;                   // e*CAP + c
  int tok = etok[rc];
  int d = threadIdx.x * 4;
  float4 v = make_float4(0.f,0.f,0.f,0.f);
  if (tok >= 0) v = *(const float4*)(h + (size_t)tok*D_ + d);
  union { u16 s[4]; uint2 u; } hi, lo;
  hi.s[0]=f2bf(v.x); lo.s[0]=f2bf(v.x - bf2f(hi.s[0]));
  hi.s[1]=f2bf(v.y); lo.s[1]=f2bf(v.y - bf2f(hi.s[1]));
  hi.s[2]=f2bf(v.z); lo.s[2]=f2bf(v.z - bf2f(hi.s[2]));
  hi.s[3]=f2bf(v.w); lo.s[3]=f2bf(v.w - bf2f(hi.s[3]));
  *(uint2*)(xhi + (size_t)rc*D_ + d) = hi.u;
  *(uint2*)(xlo + (size_t)rc*D_ + d) = lo.u;
}

// ---------------- expert GEMM: [E]: out(256xN) = A(256xK) * B(KxN) ----------------
// A: bf16 hi/lo rows (K-contig). B: fp32 K-major in global; transposed+converted into LDS.
// SPLIT: 3-MFMA split-bf16 (~fp32 accuracy). GELU: out = gelu(acc) stored hi(/lo) bf16,
// else raw fp32.
template<bool SPLIT, bool GELU>
__global__ __launch_bounds__(256, 2) void k_gemm_expert(
    const u16* __restrict__ Ahi, const u16* __restrict__ Alo,
    const float* __restrict__ Bw,
    u16* __restrict__ Ohi, u16* __restrict__ Olo, float* __restrict__ Of,
    int N, int K, int ntiles){
  constexpr int NB = SPLIT ? 2 : 1;
  __shared__ __align__(16) u16 As[NB*128*32];   // [m][k] 64B rows
  __shared__ __align__(16) u16 Bs[NB*128*40];   // [n][k] 80B rows (16B pad)
  u16* AsLo = As + 128*32;
  u16* BsLo = Bs + 128*40;
  int bid = blockIdx.x;
  int e = bid / (2*ntiles);
  int rem = bid - e*2*ntiles;
  int nt = rem >> 1, mt = rem & 1;
  int m0 = mt*128, n0 = nt*128;
  int tid = threadIdx.x;
  int l = tid & 63;
  int wr = tid >> 7, wc = (tid >> 6) & 1;
  int lr = l & 15, lq = l >> 4;
  int kb = tid >> 5, nb = tid & 31;
  const u16* Ah = Ahi + (size_t)e*256*K;
  const u16* Al = SPLIT ? (Alo + (size_t)e*256*K) : (const u16*)nullptr;
  const float* Bb = Bw + (size_t)e*K*N;
  f32x4 acc[4][4];
  #pragma unroll
  for (int i=0;i<4;++i)
    #pragma unroll
    for (int j=0;j<4;++j)
      #pragma unroll
      for (int c=0;c<4;++c) acc[i][j][c] = 0.f;

  for (int k0 = 0; k0 < K; k0 += 32){
    __syncthreads();
    #pragma unroll
    for (int r=0;r<2;++r){
      int o = r*4096 + tid*16;
      int row = o >> 6, kk = (o & 63) >> 1;
      gl_lds16(Ah + (size_t)(m0+row)*K + k0 + kk, (char*)As + o);
      if constexpr (SPLIT)
        gl_lds16(Al + (size_t)(m0+row)*K + k0 + kk, (char*)AsLo + o);
    }
    {
      const float* bs = Bb + (size_t)(k0 + kb*4)*N + n0 + nb*4;
      float4 r0 = *(const float4*)bs;
      float4 r1 = *(const float4*)(bs + N);
      float4 r2 = *(const float4*)(bs + 2*N);
      float4 r3 = *(const float4*)(bs + 3*N);
      float cv[4][4] = {{r0.x,r1.x,r2.x,r3.x},{r0.y,r1.y,r2.y,r3.y},
                        {r0.z,r1.z,r2.z,r3.z},{r0.w,r1.w,r2.w,r3.w}};
      #pragma unroll
      for (int j=0;j<4;++j){
        int n = nb*4 + j;
        union { u16 s[4]; uint2 u; } hi, lo;
        #pragma unroll
        for (int i=0;i<4;++i){
          hi.s[i] = f2bf(cv[j][i]);
          if constexpr (SPLIT) lo.s[i] = f2bf(cv[j][i] - bf2f(hi.s[i]));
        }
        *(uint2*)((char*)Bs + n*80 + kb*8) = hi.u;
        if constexpr (SPLIT) *(uint2*)((char*)BsLo + n*80 + kb*8) = lo.u;
      }
    }
    __syncthreads();
    bf16x8 ah[4], al[4], bh[4], bl[4];
    #pragma unroll
    for (int mi=0;mi<4;++mi){
      int o = (wr*64 + mi*16 + lr)*64 + lq*16;
      ah[mi] = *(const bf16x8*)((const char*)As + o);
      if constexpr (SPLIT) al[mi] = *(const bf16x8*)((const char*)AsLo + o);
    }
    #pragma unroll
    for (int ni=0;ni<4;++ni){
      int o = (wc*64 + ni*16 + lr)*80 + lq*16;
      bh[ni] = *(const bf16x8*)((const char*)Bs + o);
      if constexpr (SPLIT) bl[ni] = *(const bf16x8*)((const char*)BsLo + o);
    }
    #pragma unroll
    for (int mi=0;mi<4;++mi)
      #pragma unroll
      for (int ni=0;ni<4;++ni){
        acc[mi][ni] = mfma16(ah[mi], bh[ni], acc[mi][ni]);
        if constexpr (SPLIT){
          acc[mi][ni] = mfma16(al[mi], bh[ni], acc[mi][ni]);
          acc[mi][ni] = mfma16(ah[mi], bl[ni], acc[mi][ni]);
        }
      }
  }
  #pragma unroll
  for (int mi=0;mi<4;++mi)
    #pragma unroll
    for (int ni=0;ni<4;++ni)
      #pragma unroll
      for (int j=0;j<4;++j){
        int row = m0 + wr*64 + mi*16 + lq*4 + j;
        int col = n0 + wc*64 + ni*16 + lr;
        float x = acc[mi][ni][j];
        size_t idx = ((size_t)e*256 + row)*N + col;
        if constexpr (GELU){
          float y = gelu_tanh(x);
          u16 hv = f2bf(y);
          Ohi[idx] = hv;
          if constexpr (SPLIT) Olo[idx] = f2bf(y - bf2f(hv));
        } else {
          Of[idx] = x;
        }
      }
}

// ---------------- combine: h = (1-rho)*h + sum_k cw_k * y_k ----------------
__global__ __launch_bounds__(256) void k_combine(float* __restrict__ h,
    const float* __restrict__ Y2, const int* __restrict__ top2,
    const float* __restrict__ p2, const int* __restrict__ kept){
  int t = blockIdx.x;
  int e0 = top2[t*2], e1 = top2[t*2+1];
  int r0 = kept[t*2], r1 = kept[t*2+1];
  float w0 = (r0 >= 0) ? p2[t*2]   : 0.f;
  float w1 = (r1 >= 0) ? p2[t*2+1] : 0.f;
  float om = 1.f - w0 - w1;
  int d = threadIdx.x * 4;
  float4 v = *(const float4*)(h + (size_t)t*D_ + d);
  float ox = v.x*om, oy = v.y*om, oz = v.z*om, ow = v.w*om;
  if (r0 >= 0){
    float4 y = *(const float4*)(Y2 + ((size_t)e0*CAP_ + r0)*D_ + d);
    ox += w0*y.x; oy += w0*y.y; oz += w0*y.z; ow += w0*y.w;
  }
  if (r1 >= 0){
    float4 y = *(const float4*)(Y2 + ((size_t)e1*CAP_ + r1)*D_ + d);
    ox += w1*y.x; oy += w1*y.y; oz += w1*y.z; ow += w1*y.w;
  }
  *(float4*)(h + (size_t)t*D_ + d) = make_float4(ox, oy, oz, ow);
}

// ---------------- RMSNorm -> bf16 ----------------
__global__ __launch_bounds__(256) void k_rmsnorm(const float* __restrict__ h,
    const float* __restrict__ g, u16* __restrict__ hn){
  int t = blockIdx.x;
  int d = threadIdx.x * 4;
  int w = threadIdx.x >> 6, l = threadIdx.x & 63;
  __shared__ float red[4];
  float4 v = *(const float4*)(h + (size_t)t*D_ + d);
  float ss = v.x*v.x + v.y*v.y + v.z*v.z + v.w*v.w;
  #pragma unroll
  for (int off=32; off; off>>=1) ss += __shfl_xor(ss, off, 64);
  if (l == 0) red[w] = ss;
  __syncthreads();
  float tot = red[0] + red[1] + red[2] + red[3];
  float sc = rsqrtf(tot * (1.f/D_) + 1e-5f);
  float4 gs = *(const float4*)(g + d);
  union { u16 s[4]; uint2 u; } o;
  o.s[0] = f2bf(v.x*sc*gs.x); o.s[1] = f2bf(v.y*sc*gs.y);
  o.s[2] = f2bf(v.z*sc*gs.z); o.s[3] = f2bf(v.w*sc*gs.w);
  *(uint2*)(hn + (size_t)t*D_ + d) = o.u;
}

// ---------------- final GEMM: out(2048x32000) = hn(2048x1024) * embed_bf16^T ----------------
__global__ __launch_bounds__(256, 2) void k_gemm_final(const u16* __restrict__ A,
    const u16* __restrict__ B, float* __restrict__ C){
  __shared__ __align__(16) u16 As[128*32];
  __shared__ __align__(16) u16 Bs[128*32];
  int bid = blockIdx.x;
  int m0 = (bid & 15) * 128;
  int n0 = (bid >> 4) * 128;
  int tid = threadIdx.x;
  int l = tid & 63;
  int wr = tid >> 7, wc = (tid >> 6) & 1;
  int lr = l & 15, lq = l >> 4;
  f32x4 acc[4][4];
  #pragma unroll
  for (int i=0;i<4;++i)
    #pragma unroll
    for (int j=0;j<4;++j)
      #pragma unroll
      for (int c=0;c<4;++c) acc[i][j][c] = 0.f;

  for (int k0 = 0; k0 < D_; k0 += 32){
    __syncthreads();
    #pragma unroll
    for (int r=0;r<2;++r){
      int o = r*4096 + tid*16;
      int row = o >> 6, kk = (o & 63) >> 1;
      gl_lds16(A + (size_t)(m0+row)*D_ + k0 + kk, (char*)As + o);
      gl_lds16(B + (size_t)(n0+row)*D_ + k0 + kk, (char*)Bs + o);
    }
    __syncthreads();
    bf16x8 af[4], bf[4];
    #pragma unroll
    for (int mi=0;mi<4;++mi)
      af[mi] = *(const bf16x8*)((const char*)As + (wr*64 + mi*16 + lr)*64 + lq*16);
    #pragma unroll
    for (int ni=0;ni<4;++ni)
      bf[ni] = *(const bf16x8*)((const char*)Bs + (wc*64 + ni*16 + lr)*64 + lq*16);
    #pragma unroll
    for (int mi=0;mi<4;++mi)
      #pragma unroll
      for (int ni=0;ni<4;++ni)
        acc[mi][ni] = mfma16(af[mi], bf[ni], acc[mi][ni]);
  }
  #pragma unroll
  for (int mi=0;mi<4;++mi)
    #pragma unroll
    for (int ni=0;ni<4;++ni)
      #pragma unroll
      for (int j=0;j<4;++j){
        int row = m0 + wr*64 + mi*16 + lq*4 + j;
        int col = n0 + wc*64 + ni*16 + lr;
        C[(size_t)row * V_ + col] = acc[mi][ni][j];
      }
}

extern "C" void kernel_launch(void* const* d_in, const int* in_sizes, int n_in,
                              void* d_out, int out_size, void* d_ws, size_t ws_size,
                              hipStream_t stream){
  const int*   ids  = (const int*)d_in[0];
  const float* embW = (const float*)d_in[1];
  const float* lns  = (const float*)d_in[2];
  const float* WrA  = (const float*)d_in[3];
  const float* W1A  = (const float*)d_in[4];
  const float* W2A  = (const float*)d_in[5];
  float* out = (float*)d_out;
  char* ws = (char*)d_ws;
  const size_t MB = 1u << 20;

  float* h      = (float*)(ws);                       // 8 MB
  float* logits = (float*)(ws + 8*MB);                // 128 KB
  unsigned char* mask = (unsigned char*)(ws + 8*MB + 131072);
  int*   top2v  = (int*)(ws + 8*MB + 131072 + 32768);
  float* p2     = (float*)(ws + 8*MB + 131072 + 32768 + 16384);
  int*   kept   = (int*)(ws + 8*MB + 131072 + 32768 + 32768);
  int*   etok   = (int*)(ws + 8*MB + 131072 + 32768 + 49152);
  u16*   xhi  = (u16*)(ws + 9*MB);                    // 8 MB
  u16*   xlo  = (u16*)(ws + 17*MB);                   // 8 MB
  float* y2   = (float*)(ws + 9*MB);                  // 16 MB, aliases xin (dead by then)
  u16*   y1hi = (u16*)(ws + 25*MB);                   // 16 MB
  u16*   y1lo = (u16*)(ws + 41*MB);                   // 16 MB
  u16*   hn   = (u16*)(ws + 57*MB);                   // 4 MB
  u16*   ebf  = (u16*)(ws + 61*MB);                   // 62.5 MB

  k_embed<<<T_, 256, 0, stream>>>(ids, embW, h);
  k_cvtw<<<(V_*D_)/(256*8), 256, 0, stream>>>(embW, ebf);

  for (int hop = 0; hop < 2; ++hop){
    const float* Wr = WrA + (size_t)hop*D_*E_;
    const float* W1 = W1A + (size_t)hop*E_*D_*DFF_;
    const float* W2 = W2A + (size_t)hop*E_*DFF_*D_;
    k_router<<<T_/4, 256, 0, stream>>>(h, Wr, logits, mask, top2v, p2);
    k_init_etok<<<E_*CAP_/256, 256, 0, stream>>>(etok);
    k_capacity<<<T_*2/4, 256, 0, stream>>>(logits, mask, top2v, kept, etok);
    k_gather<<<E_*CAP_, 256, 0, stream>>>(h, etok, xhi, xlo);
    if (hop == 0){
      k_gemm_expert<true , true ><<<E_*2*(DFF_/128), 256, 0, stream>>>(
          xhi, xlo, W1, y1hi, y1lo, nullptr, DFF_, D_, DFF_/128);
      k_gemm_expert<true , false><<<E_*2*(D_/128), 256, 0, stream>>>(
          y1hi, y1lo, W2, nullptr, nullptr, y2, D_, DFF_, D_/128);
    } else {
      k_gemm_expert<false, true ><<<E_*2*(DFF_/128), 256, 0, stream>>>(
          xhi, nullptr, W1, y1hi, nullptr, nullptr, DFF_, D_, DFF_/128);
      k_gemm_expert<false, false><<<E_*2*(D_/128), 256, 0, stream>>>(
          y1hi, nullptr, W2, nullptr, nullptr, y2, D_, DFF_, D_/128);
    }
    k_combine<<<T_, 256, 0, stream>>>(h, y2, top2v, p2, kept);
  }

  k_rmsnorm<<<T_, 256, 0, stream>>>(h, lns, hn);
  k_gemm_final<<<(T_/128)*(V_/128), 256, 0, stream>>>(hn, ebf, out);
}

// Round 2
// 665.912 us; speedup vs baseline: 1.0787x; 1.0787x over previous
//
#include <hip/hip_runtime.h>
#include <stdint.h>

#define T_ 2048
#define V_ 32000
#define D_ 1024
#define E_ 16
#define CAP_ 256
#define DFF_ 2048

typedef unsigned short u16;
typedef unsigned int u32;
typedef __bf16 bf16x8 __attribute__((ext_vector_type(8)));
typedef float f32x4 __attribute__((ext_vector_type(4)));

__device__ __forceinline__ u16 f2bf(float f){
  u32 u = __float_as_uint(f);
  u32 r = u + 0x7FFFu + ((u >> 16) & 1u);
  return (u16)(r >> 16);
}
__device__ __forceinline__ float bf2f(u16 s){ return __uint_as_float(((u32)s) << 16); }

__device__ __forceinline__ void gl_lds16(const void* g, void* l){
  __builtin_amdgcn_global_load_lds((const __attribute__((address_space(1))) void*)g,
                                   (__attribute__((address_space(3))) void*)l, 16, 0, 0);
}
__device__ __forceinline__ f32x4 mfma16(bf16x8 a, bf16x8 b, f32x4 c){
  return __builtin_amdgcn_mfma_f32_16x16x32_bf16(a, b, c, 0, 0, 0);
}
__device__ __forceinline__ float gelu_tanh(float x){
  float u = 0.7978845608028654f * (x + 0.044715f * x * x * x);
  return 0.5f * x * (1.0f + tanhf(u));
}

// ---------------- embedding lookup ----------------
__global__ __launch_bounds__(256) void k_embed(const int* __restrict__ ids,
    const float* __restrict__ W, float* __restrict__ h){
  int t = blockIdx.x;
  int d = threadIdx.x * 4;
  *(float4*)(h + (size_t)t*D_ + d) = *(const float4*)(W + (size_t)ids[t]*D_ + d);
}

// ---------------- embed_W fp32 -> bf16 ----------------
__global__ __launch_bounds__(256) void k_cvtw(const float* __restrict__ W, u16* __restrict__ Wb){
  size_t i = ((size_t)blockIdx.x*256 + threadIdx.x)*8;
  float4 a = *(const float4*)(W + i);
  float4 b = *(const float4*)(W + i + 4);
  union { u16 s[8]; uint4 v; } p;
  p.s[0]=f2bf(a.x); p.s[1]=f2bf(a.y); p.s[2]=f2bf(a.z); p.s[3]=f2bf(a.w);
  p.s[4]=f2bf(b.x); p.s[5]=f2bf(b.y); p.s[6]=f2bf(b.z); p.s[7]=f2bf(b.w);
  *(uint4*)(Wb + i) = p.v;
}

// ---------------- router ----------------
__global__ __launch_bounds__(256) void k_router(const float* __restrict__ h,
    const float* __restrict__ Wr, float* __restrict__ logits,
    unsigned char* __restrict__ mask, int* __restrict__ top2, float* __restrict__ p2){
  int w = threadIdx.x >> 6, l = threadIdx.x & 63;
  int t = blockIdx.x*4 + w;
  float acc[E_];
  #pragma unroll
  for (int e=0;e<E_;++e) acc[e]=0.f;
  const float* hrow = h + (size_t)t*D_;
  #pragma unroll
  for (int i=0;i<16;++i){
    int d = l + i*64;
    float hv = hrow[d];
    const float4* wr = (const float4*)(Wr + d*E_);
    float4 w0=wr[0], w1=wr[1], w2=wr[2], w3=wr[3];
    acc[0]+=hv*w0.x; acc[1]+=hv*w0.y; acc[2]+=hv*w0.z; acc[3]+=hv*w0.w;
    acc[4]+=hv*w1.x; acc[5]+=hv*w1.y; acc[6]+=hv*w1.z; acc[7]+=hv*w1.w;
    acc[8]+=hv*w2.x; acc[9]+=hv*w2.y; acc[10]+=hv*w2.z; acc[11]+=hv*w2.w;
    acc[12]+=hv*w3.x; acc[13]+=hv*w3.y; acc[14]+=hv*w3.z; acc[15]+=hv*w3.w;
  }
  #pragma unroll
  for (int off=32; off; off>>=1){
    #pragma unroll
    for (int e=0;e<E_;++e) acc[e] += __shfl_xor(acc[e], off, 64);
  }
  float mx = acc[0];
  #pragma unroll
  for (int e=1;e<E_;++e) mx = fmaxf(mx, acc[e]);
  float p[E_], s = 0.f;
  #pragma unroll
  for (int e=0;e<E_;++e){ p[e] = expf(acc[e]-mx); s += p[e]; }
  int i1 = 0; float v1 = acc[0];
  #pragma unroll
  for (int e=1;e<E_;++e) if (acc[e] > v1){ v1 = acc[e]; i1 = e; }
  int i2 = (i1==0)?1:0; float v2 = acc[i2];
  #pragma unroll
  for (int e=0;e<E_;++e) if (e!=i1 && e!=i2 && acc[e] > v2){ v2 = acc[e]; i2 = e; }
  if (l < E_){
    logits[t*E_+l] = acc[l];
    mask[t*E_+l] = (l==i1 || l==i2) ? 1 : 0;
  }
  if (l == 0){
    float inv = 1.f/s;
    top2[t*2] = i1; top2[t*2+1] = i2;
    p2[t*2] = p[i1]*inv; p2[t*2+1] = p[i2]*inv;
  }
}

__global__ __launch_bounds__(256) void k_init_etok(int* __restrict__ etok){
  etok[blockIdx.x*256 + threadIdx.x] = -1;
}

// ---------------- capacity selection ----------------
__global__ __launch_bounds__(256) void k_capacity(const float* __restrict__ logits,
    const unsigned char* __restrict__ mask, const int* __restrict__ top2,
    int* __restrict__ kept, int* __restrict__ etok){
  int w = threadIdx.x >> 6, l = threadIdx.x & 63;
  int wid = blockIdx.x*4 + w;
  int t = wid >> 1, k = wid & 1;
  int e = top2[t*2+k];
  float my = logits[t*E_+e];
  int cnt = 0;
  for (int t2 = l; t2 < T_; t2 += 64){
    if (mask[t2*E_+e]){
      float lg = logits[t2*E_+e];
      if (lg > my || (lg == my && t2 < t)) cnt++;
    }
  }
  #pragma unroll
  for (int off=32; off; off>>=1) cnt += __shfl_xor(cnt, off, 64);
  if (l == 0){
    if (cnt < CAP_){ kept[t*2+k] = cnt; etok[e*CAP_+cnt] = t; }
    else kept[t*2+k] = -1;
  }
}

// ---------------- gather ----------------
__global__ __launch_bounds__(256) void k_gather(const float* __restrict__ h,
    const int* __restrict__ etok, u16* __restrict__ xhi, u16* __restrict__ xlo){
  int rc = blockIdx.x;
  int tok = etok[rc];
  int d = threadIdx.x * 4;
  float4 v = make_float4(0.f,0.f,0.f,0.f);
  if (tok >= 0) v = *(const float4*)(h + (size_t)tok*D_ + d);
  union { u16 s[4]; uint2 u; } hi, lo;
  hi.s[0]=f2bf(v.x); lo.s[0]=f2bf(v.x - bf2f(hi.s[0]));
  hi.s[1]=f2bf(v.y); lo.s[1]=f2bf(v.y - bf2f(hi.s[1]));
  hi.s[2]=f2bf(v.z); lo.s[2]=f2bf(v.z - bf2f(hi.s[2]));
  hi.s[3]=f2bf(v.w); lo.s[3]=f2bf(v.w - bf2f(hi.s[3]));
  *(uint2*)(xhi + (size_t)rc*D_ + d) = hi.u;
  *(uint2*)(xlo + (size_t)rc*D_ + d) = lo.u;
}

// ---------------- expert GEMM ----------------
// A staged via gl_lds with 16B-chunk XOR swizzle (chunk ^ (row>>1)&3); B fp32
// loaded to regs (pipelined one K-step ahead), converted to bf16 hi/lo in VALU,
// ds_write to 80B-padded rows (reads already ~2-way).
template<bool SPLIT, bool GELU>
__global__ __launch_bounds__(256, 2) void k_gemm_expert(
    const u16* __restrict__ Ahi, const u16* __restrict__ Alo,
    const float* __restrict__ Bw,
    u16* __restrict__ Ohi, u16* __restrict__ Olo, float* __restrict__ Of,
    int N, int K, int ntiles){
  constexpr int NB = SPLIT ? 2 : 1;
  __shared__ __align__(16) u16 As[NB*128*32];
  __shared__ __align__(16) u16 Bs[NB*128*40];
  u16* AsLo = As + 128*32;
  u16* BsLo = Bs + 128*40;
  int chunk = gridDim.x >> 3;
  int bid = blockIdx.x;
  int swz = (bid & 7)*chunk + (bid >> 3);       // XCD-contiguous work ids
  int e = swz / (2*ntiles);
  int rem = swz - e*2*ntiles;
  int nt = rem >> 1, mt = rem & 1;
  int m0 = mt*128, n0 = nt*128;
  int tid = threadIdx.x;
  int l = tid & 63;
  int wr = tid >> 7, wc = (tid >> 6) & 1;
  int lr = l & 15, lq = l >> 4;
  int kb = tid >> 5, nb = tid & 31;
  const u16* Ah = Ahi + (size_t)e*256*K;
  const u16* Al = SPLIT ? (Alo + (size_t)e*256*K) : (const u16*)nullptr;
  const float* Bb = Bw + (size_t)e*K*N;
  f32x4 acc[4][4];
  #pragma unroll
  for (int i=0;i<4;++i)
    #pragma unroll
    for (int j=0;j<4;++j)
      #pragma unroll
      for (int c=0;c<4;++c) acc[i][j][c] = 0.f;

  float4 pb0, pb1, pb2, pb3;
  {
    const float* bs = Bb + (size_t)(kb*4)*N + n0 + nb*4;
    pb0 = *(const float4*)bs;
    pb1 = *(const float4*)(bs + N);
    pb2 = *(const float4*)(bs + 2*N);
    pb3 = *(const float4*)(bs + 3*N);
  }

  for (int k0 = 0; k0 < K; k0 += 32){
    __syncthreads();
    // A staging: linear LDS dest, inverse-swizzled global source
    #pragma unroll
    for (int r=0;r<2;++r){
      int o = r*4096 + tid*16;
      int row = o >> 6;
      int c = (o >> 4) & 3;
      int cs = c ^ ((row >> 1) & 3);
      gl_lds16(Ah + (size_t)(m0+row)*K + k0 + cs*8, (char*)As + o);
      if constexpr (SPLIT)
        gl_lds16(Al + (size_t)(m0+row)*K + k0 + cs*8, (char*)AsLo + o);
    }
    // convert current B regs -> LDS
    {
      float cv[4][4] = {{pb0.x,pb1.x,pb2.x,pb3.x},{pb0.y,pb1.y,pb2.y,pb3.y},
                        {pb0.z,pb1.z,pb2.z,pb3.z},{pb0.w,pb1.w,pb2.w,pb3.w}};
      #pragma unroll
      for (int j=0;j<4;++j){
        int n = nb*4 + j;
        union { u16 s[4]; uint2 u; } hi, lo;
        #pragma unroll
        for (int i=0;i<4;++i){
          hi.s[i] = f2bf(cv[j][i]);
          if constexpr (SPLIT) lo.s[i] = f2bf(cv[j][i] - bf2f(hi.s[i]));
        }
        *(uint2*)((char*)Bs + n*80 + kb*8) = hi.u;
        if constexpr (SPLIT) *(uint2*)((char*)BsLo + n*80 + kb*8) = lo.u;
      }
    }
    // prefetch next K-step's B tile into regs (latency hides under MFMA phase)
    if (k0 + 32 < K){
      const float* bs = Bb + (size_t)(k0 + 32 + kb*4)*N + n0 + nb*4;
      pb0 = *(const float4*)bs;
      pb1 = *(const float4*)(bs + N);
      pb2 = *(const float4*)(bs + 2*N);
      pb3 = *(const float4*)(bs + 3*N);
    }
    __syncthreads();
    bf16x8 ah[4], al[4], bh[4], bl[4];
    #pragma unroll
    for (int mi=0;mi<4;++mi){
      int row = wr*64 + mi*16 + lr;
      int q = lq ^ ((row >> 1) & 3);
      int o = row*64 + q*16;
      ah[mi] = *(const bf16x8*)((const char*)As + o);
      if constexpr (SPLIT) al[mi] = *(const bf16x8*)((const char*)AsLo + o);
    }
    #pragma unroll
    for (int ni=0;ni<4;++ni){
      int o = (wc*64 + ni*16 + lr)*80 + lq*16;
      bh[ni] = *(const bf16x8*)((const char*)Bs + o);
      if constexpr (SPLIT) bl[ni] = *(const bf16x8*)((const char*)BsLo + o);
    }
    #pragma unroll
    for (int mi=0;mi<4;++mi)
      #pragma unroll
      for (int ni=0;ni<4;++ni){
        acc[mi][ni] = mfma16(ah[mi], bh[ni], acc[mi][ni]);
        if constexpr (SPLIT){
          acc[mi][ni] = mfma16(al[mi], bh[ni], acc[mi][ni]);
          acc[mi][ni] = mfma16(ah[mi], bl[ni], acc[mi][ni]);
        }
      }
  }
  #pragma unroll
  for (int mi=0;mi<4;++mi)
    #pragma unroll
    for (int ni=0;ni<4;++ni)
      #pragma unroll
      for (int j=0;j<4;++j){
        int row = m0 + wr*64 + mi*16 + lq*4 + j;
        int col = n0 + wc*64 + ni*16 + lr;
        float x = acc[mi][ni][j];
        size_t idx = ((size_t)e*256 + row)*N + col;
        if constexpr (GELU){
          float y = gelu_tanh(x);
          u16 hv = f2bf(y);
          Ohi[idx] = hv;
          if constexpr (SPLIT) Olo[idx] = f2bf(y - bf2f(hv));
        } else {
          Of[idx] = x;
        }
      }
}

// ---------------- combine ----------------
__global__ __launch_bounds__(256) void k_combine(float* __restrict__ h,
    const float* __restrict__ Y2, const int* __restrict__ top2,
    const float* __restrict__ p2, const int* __restrict__ kept){
  int t = blockIdx.x;
  int e0 = top2[t*2], e1 = top2[t*2+1];
  int r0 = kept[t*2], r1 = kept[t*2+1];
  float w0 = (r0 >= 0) ? p2[t*2]   : 0.f;
  float w1 = (r1 >= 0) ? p2[t*2+1] : 0.f;
  float om = 1.f - w0 - w1;
  int d = threadIdx.x * 4;
  float4 v = *(const float4*)(h + (size_t)t*D_ + d);
  float ox = v.x*om, oy = v.y*om, oz = v.z*om, ow = v.w*om;
  if (r0 >= 0){
    float4 y = *(const float4*)(Y2 + ((size_t)e0*CAP_ + r0)*D_ + d);
    ox += w0*y.x; oy += w0*y.y; oz += w0*y.z; ow += w0*y.w;
  }
  if (r1 >= 0){
    float4 y = *(const float4*)(Y2 + ((size_t)e1*CAP_ + r1)*D_ + d);
    ox += w1*y.x; oy += w1*y.y; oz += w1*y.z; ow += w1*y.w;
  }
  *(float4*)(h + (size_t)t*D_ + d) = make_float4(ox, oy, oz, ow);
}

// ---------------- RMSNorm -> bf16 ----------------
__global__ __launch_bounds__(256) void k_rmsnorm(const float* __restrict__ h,
    const float* __restrict__ g, u16* __restrict__ hn){
  int t = blockIdx.x;
  int d = threadIdx.x * 4;
  int w = threadIdx.x >> 6, l = threadIdx.x & 63;
  __shared__ float red[4];
  float4 v = *(const float4*)(h + (size_t)t*D_ + d);
  float ss = v.x*v.x + v.y*v.y + v.z*v.z + v.w*v.w;
  #pragma unroll
  for (int off=32; off; off>>=1) ss += __shfl_xor(ss, off, 64);
  if (l == 0) red[w] = ss;
  __syncthreads();
  float tot = red[0] + red[1] + red[2] + red[3];
  float sc = rsqrtf(tot * (1.f/D_) + 1e-5f);
  float4 gs = *(const float4*)(g + d);
  union { u16 s[4]; uint2 u; } o;
  o.s[0] = f2bf(v.x*sc*gs.x); o.s[1] = f2bf(v.y*sc*gs.y);
  o.s[2] = f2bf(v.z*sc*gs.z); o.s[3] = f2bf(v.w*sc*gs.w);
  *(uint2*)(hn + (size_t)t*D_ + d) = o.u;
}

// ---------------- final GEMM: BK=64, XOR-swizzled LDS, XCD swizzle ----------------
__global__ __launch_bounds__(256, 3) void k_gemm_final(const u16* __restrict__ A,
    const u16* __restrict__ B, float* __restrict__ C){
  __shared__ __align__(16) u16 As[128*64];
  __shared__ __align__(16) u16 Bs[128*64];
  int bid = blockIdx.x;
  int swz = (bid & 7)*500 + (bid >> 3);        // 4000 % 8 == 0 -> bijective
  int m0 = (swz & 15) * 128;                    // m fastest: B-panel L2 reuse
  int n0 = (swz >> 4) * 128;
  int tid = threadIdx.x;
  int l = tid & 63;
  int wr = tid >> 7, wc = (tid >> 6) & 1;
  int lr = l & 15, lq = l >> 4;
  f32x4 acc[4][4];
  #pragma unroll
  for (int i=0;i<4;++i)
    #pragma unroll
    for (int j=0;j<4;++j)
      #pragma unroll
      for (int c=0;c<4;++c) acc[i][j][c] = 0.f;

  for (int k0 = 0; k0 < D_; k0 += 64){
    __syncthreads();
    #pragma unroll
    for (int r=0;r<4;++r){
      int o = r*4096 + tid*16;
      int row = o >> 7;
      int c = (o >> 4) & 7;
      int cs = c ^ (row & 7);
      gl_lds16(A + (size_t)(m0+row)*D_ + k0 + cs*8, (char*)As + o);
      gl_lds16(B + (size_t)(n0+row)*D_ + k0 + cs*8, (char*)Bs + o);
    }
    __syncthreads();
    #pragma unroll
    for (int kh=0; kh<2; ++kh){
      bf16x8 af[4], bf[4];
      #pragma unroll
      for (int mi=0;mi<4;++mi){
        int row = wr*64 + mi*16 + lr;
        int q = (lq + 4*kh) ^ (row & 7);
        af[mi] = *(const bf16x8*)((const char*)As + row*128 + q*16);
      }
      #pragma unroll
      for (int ni=0;ni<4;++ni){
        int row = wc*64 + ni*16 + lr;
        int q = (lq + 4*kh) ^ (row & 7);
        bf[ni] = *(const bf16x8*)((const char*)Bs + row*128 + q*16);
      }
      #pragma unroll
      for (int mi=0;mi<4;++mi)
        #pragma unroll
        for (int ni=0;ni<4;++ni)
          acc[mi][ni] = mfma16(af[mi], bf[ni], acc[mi][ni]);
    }
  }
  #pragma unroll
  for (int mi=0;mi<4;++mi)
    #pragma unroll
    for (int ni=0;ni<4;++ni)
      #pragma unroll
      for (int j=0;j<4;++j){
        int row = m0 + wr*64 + mi*16 + lq*4 + j;
        int col = n0 + wc*64 + ni*16 + lr;
        C[(size_t)row * V_ + col] = acc[mi][ni][j];
      }
}

extern "C" void kernel_launch(void* const* d_in, const int* in_sizes, int n_in,
                              void* d_out, int out_size, void* d_ws, size_t ws_size,
                              hipStream_t stream){
  const int*   ids  = (const int*)d_in[0];
  const float* embW = (const float*)d_in[1];
  const float* lns  = (const float*)d_in[2];
  const float* WrA  = (const float*)d_in[3];
  const float* W1A  = (const float*)d_in[4];
  const float* W2A  = (const float*)d_in[5];
  float* out = (float*)d_out;
  char* ws = (char*)d_ws;
  const size_t MB = 1u << 20;

  float* h      = (float*)(ws);
  float* logits = (float*)(ws + 8*MB);
  unsigned char* mask = (unsigned char*)(ws + 8*MB + 131072);
  int*   top2v  = (int*)(ws + 8*MB + 131072 + 32768);
  float* p2     = (float*)(ws + 8*MB + 131072 + 32768 + 16384);
  int*   kept   = (int*)(ws + 8*MB + 131072 + 32768 + 32768);
  int*   etok   = (int*)(ws + 8*MB + 131072 + 32768 + 49152);
  u16*   xhi  = (u16*)(ws + 9*MB);
  u16*   xlo  = (u16*)(ws + 17*MB);
  float* y2   = (float*)(ws + 9*MB);            // aliases xhi/xlo (dead by then)
  u16*   y1hi = (u16*)(ws + 25*MB);
  u16*   y1lo = (u16*)(ws + 41*MB);
  u16*   hn   = (u16*)(ws + 57*MB);
  u16*   ebf  = (u16*)(ws + 61*MB);

  k_embed<<<T_, 256, 0, stream>>>(ids, embW, h);
  k_cvtw<<<(V_*D_)/(256*8), 256, 0, stream>>>(embW, ebf);

  for (int hop = 0; hop < 2; ++hop){
    const float* Wr = WrA + (size_t)hop*D_*E_;
    const float* W1 = W1A + (size_t)hop*E_*D_*DFF_;
    const float* W2 = W2A + (size_t)hop*E_*DFF_*D_;
    k_router<<<T_/4, 256, 0, stream>>>(h, Wr, logits, mask, top2v, p2);
    k_init_etok<<<E_*CAP_/256, 256, 0, stream>>>(etok);
    k_capacity<<<T_*2/4, 256, 0, stream>>>(logits, mask, top2v, kept, etok);
    k_gather<<<E_*CAP_, 256, 0, stream>>>(h, etok, xhi, xlo);
    if (hop == 0){
      k_gemm_expert<true , true ><<<E_*2*(DFF_/128), 256, 0, stream>>>(
          xhi, xlo, W1, y1hi, y1lo, nullptr, DFF_, D_, DFF_/128);
      k_gemm_expert<true , false><<<E_*2*(D_/128), 256, 0, stream>>>(
          y1hi, y1lo, W2, nullptr, nullptr, y2, D_, DFF_, D_/128);
    } else {
      k_gemm_expert<false, true ><<<E_*2*(DFF_/128), 256, 0, stream>>>(
          xhi, nullptr, W1, y1hi, nullptr, nullptr, DFF_, D_, DFF_/128);
      k_gemm_expert<false, false><<<E_*2*(D_/128), 256, 0, stream>>>(
          y1hi, nullptr, W2, nullptr, nullptr, y2, D_, DFF_, D_/128);
    }
    k_combine<<<T_, 256, 0, stream>>>(h, y2, top2v, p2, kept);
  }

  k_rmsnorm<<<T_, 256, 0, stream>>>(h, lns, hn);
  k_gemm_final<<<(T_/128)*(V_/128), 256, 0, stream>>>(hn, ebf, out);
}